// Round 1
// baseline (431.534 us; speedup 1.0000x reference)
//
#include <hip/hip_runtime.h>

// QuantizedLinear: out[m,n] = (clamp(round(x/as))·as) @ (W^T·ws) + bias
// Exact int8 path: out = (sum_k xq*wq) * (as*ws) + bias  (int32 exact, K=4096*128*128 < 2^31)

#define MD 8192   // B*S
#define ND 4096   // OUT
#define KD 4096   // IN
#define KT (KD / 64)   // 64 K-tiles of 64

typedef int   int4v   __attribute__((ext_vector_type(4)));
typedef float float4v __attribute__((ext_vector_type(4)));

// Tiled int8 layout: element (r,k) of a [R][KD] matrix lives at
//   sub = (r/16)*KT + k/64 ; lane = ((k%64)/16)*16 + (r%16) ; byte = k%16
//   offset = sub*1024 + lane*16 + byte
// This is exactly the mfma_i32_16x16x64_i8 fragment order, so the GEMM's
// global_load_lds is a linear 1KiB copy and ds_read_b128 is conflict-free.

__device__ __forceinline__ int quant1(float v, float s) {
  float q = rintf(v / s);                 // matches jnp.round(x/s): half-to-even
  q = fmaxf(-128.0f, fminf(127.0f, q));
  return ((int)q) & 0xff;
}

__global__ __launch_bounds__(256) void quant_x_kernel(
    const float* __restrict__ x, const float* __restrict__ as_p,
    signed char* __restrict__ aq) {
  const float s = as_p[0];
  int tid  = blockIdx.x * 256 + threadIdx.x;
  int sub  = tid >> 6;
  int lane = tid & 63;
  int mt = sub / KT;
  int kt = sub - mt * KT;
  int m = mt * 16 + (lane & 15);
  int k = kt * 64 + (lane >> 4) * 16;
  const float* src = x + (size_t)m * KD + k;
  int4v o;
#pragma unroll
  for (int i = 0; i < 4; ++i) {
    float4v v = *(const float4v*)(src + i * 4);
    o[i] = quant1(v.x, s) | (quant1(v.y, s) << 8) |
           (quant1(v.z, s) << 16) | (quant1(v.w, s) << 24);
  }
  *(int4v*)(aq + (size_t)sub * 1024 + lane * 16) = o;  // contiguous 4KB/block
}

__global__ __launch_bounds__(256) void pack_w_kernel(
    const int* __restrict__ w, signed char* __restrict__ wq) {
  int tid  = blockIdx.x * 256 + threadIdx.x;
  int sub  = tid >> 6;
  int lane = tid & 63;
  int nt = sub / KT;
  int kt = sub - nt * KT;
  int n = nt * 16 + (lane & 15);
  int k = kt * 64 + (lane >> 4) * 16;
  const int* src = w + (size_t)n * KD + k;
  int4v o;
#pragma unroll
  for (int i = 0; i < 4; ++i) {
    int4v v = *(const int4v*)(src + i * 4);
    o[i] = (v.x & 0xff) | ((v.y & 0xff) << 8) |
           ((v.z & 0xff) << 16) | ((v.w & 0xff) << 24);
  }
  *(int4v*)(wq + (size_t)sub * 1024 + lane * 16) = o;
}

// 128x128 tile, BK=64, 4 waves in 2x2, each wave owns 64x64 (4x4 frags of 16x16).
__global__ __launch_bounds__(256) void gemm_i8_kernel(
    const signed char* __restrict__ aq, const signed char* __restrict__ wq,
    const float* __restrict__ ws_p, const float* __restrict__ as_p,
    const float* __restrict__ bias, float* __restrict__ out) {
  __shared__ signed char lds_a[8192];
  __shared__ signed char lds_b[8192];

  // XCD-bijective swizzle (gridDim = 2048, divisible by 8)
  int nwg = gridDim.x;
  int cpx = nwg >> 3;
  int bid = blockIdx.x;
  int wg  = (bid & 7) * cpx + (bid >> 3);
  const int NT = ND / 128;      // 32
  int tm = wg / NT;
  int tn = wg - tm * NT;

  int tid  = threadIdx.x;
  int lane = tid & 63;
  int wv   = tid >> 6;          // wave 0..3
  int wr   = wv >> 1;           // wave row 0..1 (64-row half)
  int wc   = wv & 1;            // wave col 0..1 (64-col half)

  const size_t a_base = (size_t)(tm * 8) * KT * 1024;  // 8 m-subtiles per tile
  const size_t b_base = (size_t)(tn * 8) * KT * 1024;  // 8 n-subtiles per tile

  int4v acc[4][4];
#pragma unroll
  for (int i = 0; i < 4; ++i)
#pragma unroll
    for (int j = 0; j < 4; ++j) acc[i][j] = (int4v){0, 0, 0, 0};

  for (int kt = 0; kt < KT; ++kt) {
    // stage: each wave copies 2 A-subtiles + 2 B-subtiles (1KiB each, linear)
#pragma unroll
    for (int j = 0; j < 2; ++j) {
      int ia = wv + j * 4;
      const signed char* ga = aq + a_base + ((size_t)ia * KT + kt) * 1024 + lane * 16;
      __builtin_amdgcn_global_load_lds(
          (const __attribute__((address_space(1))) void*)ga,
          (__attribute__((address_space(3))) void*)(lds_a + ia * 1024), 16, 0, 0);
      const signed char* gb = wq + b_base + ((size_t)ia * KT + kt) * 1024 + lane * 16;
      __builtin_amdgcn_global_load_lds(
          (const __attribute__((address_space(1))) void*)gb,
          (__attribute__((address_space(3))) void*)(lds_b + ia * 1024), 16, 0, 0);
    }
    __syncthreads();   // compiler emits vmcnt(0) drain before barrier

    int4v afrag[4], bfrag[4];
#pragma unroll
    for (int rb = 0; rb < 4; ++rb)
      afrag[rb] = *(const int4v*)(lds_a + (wr * 4 + rb) * 1024 + lane * 16);
#pragma unroll
    for (int cb = 0; cb < 4; ++cb)
      bfrag[cb] = *(const int4v*)(lds_b + (wc * 4 + cb) * 1024 + lane * 16);

#pragma unroll
    for (int rb = 0; rb < 4; ++rb)
#pragma unroll
      for (int cb = 0; cb < 4; ++cb)
        acc[rb][cb] = __builtin_amdgcn_mfma_i32_16x16x64_i8(
            afrag[rb], bfrag[cb], acc[rb][cb], 0, 0, 0);

    __syncthreads();
  }

  // epilogue: C/D 16x16 layout: col = lane&15, row = (lane>>4)*4 + reg
  float scale = ws_p[0] * as_p[0];
  int col0 = tn * 128 + wc * 64 + (lane & 15);
  int row0 = tm * 128 + wr * 64 + ((lane >> 4) << 2);
  float bv[4];
#pragma unroll
  for (int cb = 0; cb < 4; ++cb) bv[cb] = bias[col0 + cb * 16];
#pragma unroll
  for (int rb = 0; rb < 4; ++rb) {
#pragma unroll
    for (int cb = 0; cb < 4; ++cb) {
      int col = col0 + cb * 16;
#pragma unroll
      for (int j = 0; j < 4; ++j) {
        int row = row0 + rb * 16 + j;
        out[(size_t)row * ND + col] = (float)acc[rb][cb][j] * scale + bv[cb];
      }
    }
  }
}

extern "C" void kernel_launch(void* const* d_in, const int* in_sizes, int n_in,
                              void* d_out, int out_size, void* d_ws, size_t ws_size,
                              hipStream_t stream) {
  const float* x    = (const float*)d_in[0];
  const int*   qw   = (const int*)d_in[1];
  const float* wsc  = (const float*)d_in[2];
  const float* asc  = (const float*)d_in[3];
  const float* bias = (const float*)d_in[4];
  float* out = (float*)d_out;

  signed char* aq = (signed char*)d_ws;                       // 32 MiB
  signed char* wq = aq + (size_t)MD * KD;                     // 16 MiB

  quant_x_kernel<<<(MD * KD / 16) / 256, 256, 0, stream>>>(x, asc, aq);
  pack_w_kernel<<<(ND * KD / 16) / 256, 256, 0, stream>>>(qw, wq);
  gemm_i8_kernel<<<(MD / 128) * (ND / 128), 256, 0, stream>>>(aq, wq, wsc, asc, bias, out);
}

// Round 3
// 411.464 us; speedup vs baseline: 1.0488x; 1.0488x over previous
//
#include <hip/hip_runtime.h>

// QuantizedLinear: out = (sum_k xq*wq) * (as*ws) + bias  (int32 exact path)
// R2: LDS-transpose quant/pack kernels (coalesced reads AND writes).

#define MD 8192   // B*S
#define ND 4096   // OUT
#define KD 4096   // IN
#define KT (KD / 64)   // 64 K-subtiles of 64 per row-block

typedef int   int4v   __attribute__((ext_vector_type(4)));
typedef float float4v __attribute__((ext_vector_type(4)));

// Tiled int8 layout: element (r,k) lives at
//   sub = (r/16)*KT + k/64 ; lane16 = ((k%64)/16)*16 + (r%16) ; byte = k%16
//   offset = sub*1024 + lane16*16 + byte
// == mfma_i32_16x16x64_i8 fragment order: GEMM's global_load_lds is linear.

__device__ __forceinline__ unsigned int quant1(float v, float s) {
  float q = rintf(v / s);                 // matches jnp.round(x/s)
  q = fmaxf(-128.0f, fminf(127.0f, q));
  return ((unsigned int)(int)q) & 0xffu;
}

// Block: 64 rows x 256 cols slab. Phase1: coalesced read + swizzled LDS
// scatter. Phase2: ds_read_b128 + contiguous 4KB global writes.
// Swizzle: linear dword idx = subL*256 + kgroup*64 + rr*4 + c ;
//          X = idx>>6 ; idx' = X*64 + ((rr ^ (X&15))<<2) + c
__global__ __launch_bounds__(256) void quant_x_kernel(
    const float* __restrict__ x, const float* __restrict__ as_p,
    signed char* __restrict__ aq) {
  __shared__ unsigned int lds[4096];     // 16 KB
  const float s = as_p[0];
  int bid = blockIdx.x;
  int r0 = (bid >> 4) * 64;
  int k0 = (bid & 15) * 256;
  int tid = threadIdx.x, lane = tid & 63, wv = tid >> 6;

  // phase 1: wave wv handles rows r0+wv*16 .. +15; lane covers 4 cols
  int subL = wv * 4 + (lane >> 4);       // (rowlocal/16)*4 + klocal/64
  int kgroup = (lane & 15) >> 2;
  int c = lane & 3;
  int X = subL * 4 + kgroup;
  int xm = X & 15;
  const float* src = x + (size_t)(r0 + wv * 16) * KD + k0 + lane * 4;
#pragma unroll
  for (int i = 0; i < 16; ++i) {
    float4v v = *(const float4v*)(src + (size_t)i * KD);
    unsigned int d = quant1(v.x, s) | (quant1(v.y, s) << 8) |
                     (quant1(v.z, s) << 16) | (quant1(v.w, s) << 24);
    lds[X * 64 + ((i ^ xm) << 2) + c] = d;
  }
  __syncthreads();

  // phase 2: 4 contiguous 4KB output runs (one per 16-row group a)
  size_t obase = ((size_t)(r0 >> 4) * KT + (k0 >> 6)) * 1024;
  int y = tid & 15;
#pragma unroll
  for (int a = 0; a < 4; ++a) {
    int Xr = (a * 4 + (tid >> 6)) * 4 + ((tid & 63) >> 4);
    int4v vv = *(const int4v*)((const char*)lds + Xr * 256 + ((y ^ (Xr & 15)) << 4));
    *(int4v*)(aq + obase + (size_t)a * KT * 1024 + tid * 16) = vv;
  }
}

__global__ __launch_bounds__(256) void pack_w_kernel(
    const int* __restrict__ w, signed char* __restrict__ wq) {
  __shared__ unsigned int lds[4096];
  int bid = blockIdx.x;
  int r0 = (bid >> 4) * 64;
  int k0 = (bid & 15) * 256;
  int tid = threadIdx.x, lane = tid & 63, wv = tid >> 6;

  int subL = wv * 4 + (lane >> 4);
  int kgroup = (lane & 15) >> 2;
  int c = lane & 3;
  int X = subL * 4 + kgroup;
  int xm = X & 15;
  const int* src = w + (size_t)(r0 + wv * 16) * KD + k0 + lane * 4;
#pragma unroll
  for (int i = 0; i < 16; ++i) {
    int4v v = *(const int4v*)(src + (size_t)i * KD);
    unsigned int d = (v.x & 0xff) | ((v.y & 0xff) << 8) |
                     ((v.z & 0xff) << 16) | ((v.w & 0xff) << 24);
    lds[X * 64 + ((i ^ xm) << 2) + c] = d;
  }
  __syncthreads();

  size_t obase = ((size_t)(r0 >> 4) * KT + (k0 >> 6)) * 1024;
  int y = tid & 15;
#pragma unroll
  for (int a = 0; a < 4; ++a) {
    int Xr = (a * 4 + (tid >> 6)) * 4 + ((tid & 63) >> 4);
    int4v vv = *(const int4v*)((const char*)lds + Xr * 256 + ((y ^ (Xr & 15)) << 4));
    *(int4v*)(wq + obase + (size_t)a * KT * 1024 + tid * 16) = vv;
  }
}

// 128x128 tile, BK=64, 4 waves in 2x2, each wave owns 64x64 (4x4 frags of 16x16).
__global__ __launch_bounds__(256) void gemm_i8_kernel(
    const signed char* __restrict__ aq, const signed char* __restrict__ wq,
    const float* __restrict__ ws_p, const float* __restrict__ as_p,
    const float* __restrict__ bias, float* __restrict__ out) {
  __shared__ signed char lds_a[8192];
  __shared__ signed char lds_b[8192];

  // XCD-bijective swizzle (gridDim = 2048, divisible by 8)
  int nwg = gridDim.x;
  int cpx = nwg >> 3;
  int bid = blockIdx.x;
  int wg  = (bid & 7) * cpx + (bid >> 3);
  const int NT = ND / 128;      // 32
  int tm = wg / NT;
  int tn = wg - tm * NT;

  int tid  = threadIdx.x;
  int lane = tid & 63;
  int wv   = tid >> 6;          // wave 0..3
  int wr   = wv >> 1;
  int wc   = wv & 1;

  const size_t a_base = (size_t)(tm * 8) * KT * 1024;
  const size_t b_base = (size_t)(tn * 8) * KT * 1024;

  int4v acc[4][4];
#pragma unroll
  for (int i = 0; i < 4; ++i)
#pragma unroll
    for (int j = 0; j < 4; ++j) acc[i][j] = (int4v){0, 0, 0, 0};

  for (int kt = 0; kt < KT; ++kt) {
#pragma unroll
    for (int j = 0; j < 2; ++j) {
      int ia = wv + j * 4;
      const signed char* ga = aq + a_base + ((size_t)ia * KT + kt) * 1024 + lane * 16;
      __builtin_amdgcn_global_load_lds(
          (const __attribute__((address_space(1))) void*)ga,
          (__attribute__((address_space(3))) void*)(lds_a + ia * 1024), 16, 0, 0);
      const signed char* gb = wq + b_base + ((size_t)ia * KT + kt) * 1024 + lane * 16;
      __builtin_amdgcn_global_load_lds(
          (const __attribute__((address_space(1))) void*)gb,
          (__attribute__((address_space(3))) void*)(lds_b + ia * 1024), 16, 0, 0);
    }
    __syncthreads();

    int4v afrag[4], bfrag[4];
#pragma unroll
    for (int rb = 0; rb < 4; ++rb)
      afrag[rb] = *(const int4v*)(lds_a + (wr * 4 + rb) * 1024 + lane * 16);
#pragma unroll
    for (int cb = 0; cb < 4; ++cb)
      bfrag[cb] = *(const int4v*)(lds_b + (wc * 4 + cb) * 1024 + lane * 16);

#pragma unroll
    for (int rb = 0; rb < 4; ++rb)
#pragma unroll
      for (int cb = 0; cb < 4; ++cb)
        acc[rb][cb] = __builtin_amdgcn_mfma_i32_16x16x64_i8(
            afrag[rb], bfrag[cb], acc[rb][cb], 0, 0, 0);

    __syncthreads();
  }

  float scale = ws_p[0] * as_p[0];
  int col0 = tn * 128 + wc * 64 + (lane & 15);
  int row0 = tm * 128 + wr * 64 + ((lane >> 4) << 2);
  float bv[4];
#pragma unroll
  for (int cb = 0; cb < 4; ++cb) bv[cb] = bias[col0 + cb * 16];
#pragma unroll
  for (int rb = 0; rb < 4; ++rb) {
#pragma unroll
    for (int cb = 0; cb < 4; ++cb) {
      int col = col0 + cb * 16;
#pragma unroll
      for (int j = 0; j < 4; ++j) {
        int row = row0 + rb * 16 + j;
        out[(size_t)row * ND + col] = (float)acc[rb][cb][j] * scale + bv[cb];
      }
    }
  }
}

extern "C" void kernel_launch(void* const* d_in, const int* in_sizes, int n_in,
                              void* d_out, int out_size, void* d_ws, size_t ws_size,
                              hipStream_t stream) {
  const float* x    = (const float*)d_in[0];
  const int*   qw   = (const int*)d_in[1];
  const float* wsc  = (const float*)d_in[2];
  const float* asc  = (const float*)d_in[3];
  const float* bias = (const float*)d_in[4];
  float* out = (float*)d_out;

  signed char* aq = (signed char*)d_ws;                       // 32 MiB
  signed char* wq = aq + (size_t)MD * KD;                     // 16 MiB

  quant_x_kernel<<<(MD / 64) * (KD / 256), 256, 0, stream>>>(x, asc, aq);
  pack_w_kernel<<<(ND / 64) * (KD / 256), 256, 0, stream>>>(qw, wq);
  gemm_i8_kernel<<<(MD / 128) * (ND / 128), 256, 0, stream>>>(aq, wq, wsc, asc, bias, out);
}

// Round 6
// 388.732 us; speedup vs baseline: 1.1101x; 1.0585x over previous
//
#include <hip/hip_runtime.h>

// QuantizedLinear: out = (sum_k xq*wq) * (as*ws) + bias  (int32 exact path)
// R4: GEMM v2 — 256x256 tile, 8 waves, double-buffered LDS, early stage issue.
// quant_x / pack_w unchanged from R3 (controls).

#define MD 8192   // B*S
#define ND 4096   // OUT
#define KD 4096   // IN
#define KT (KD / 64)   // 64 K-subtiles of 64

typedef int   int4v   __attribute__((ext_vector_type(4)));
typedef float float4v __attribute__((ext_vector_type(4)));

// Tiled int8 layout: element (r,k) lives at
//   sub = (r/16)*KT + k/64 ; lane16 = ((k%64)/16)*16 + (r%16) ; byte = k%16
//   offset = sub*1024 + lane16*16 + byte
// == mfma_i32_16x16x64_i8 fragment order: staging is linear 1KB copies and
// every ds_read_b128 is lane*16 within a 1KB subtile (conflict-free).

__device__ __forceinline__ unsigned int quant1(float v, float s) {
  float q = rintf(v / s);                 // matches jnp.round(x/s)
  q = fmaxf(-128.0f, fminf(127.0f, q));
  return ((unsigned int)(int)q) & 0xffu;
}

__global__ __launch_bounds__(256) void quant_x_kernel(
    const float* __restrict__ x, const float* __restrict__ as_p,
    signed char* __restrict__ aq) {
  __shared__ unsigned int lds[4096];     // 16 KB
  const float s = as_p[0];
  int bid = blockIdx.x;
  int r0 = (bid >> 4) * 64;
  int k0 = (bid & 15) * 256;
  int tid = threadIdx.x, lane = tid & 63, wv = tid >> 6;

  int subL = wv * 4 + (lane >> 4);
  int kgroup = (lane & 15) >> 2;
  int c = lane & 3;
  int X = subL * 4 + kgroup;
  int xm = X & 15;
  const float* src = x + (size_t)(r0 + wv * 16) * KD + k0 + lane * 4;
#pragma unroll
  for (int i = 0; i < 16; ++i) {
    float4v v = *(const float4v*)(src + (size_t)i * KD);
    unsigned int d = quant1(v.x, s) | (quant1(v.y, s) << 8) |
                     (quant1(v.z, s) << 16) | (quant1(v.w, s) << 24);
    lds[X * 64 + ((i ^ xm) << 2) + c] = d;
  }
  __syncthreads();

  size_t obase = ((size_t)(r0 >> 4) * KT + (k0 >> 6)) * 1024;
  int y = tid & 15;
#pragma unroll
  for (int a = 0; a < 4; ++a) {
    int Xr = (a * 4 + (tid >> 6)) * 4 + ((tid & 63) >> 4);
    int4v vv = *(const int4v*)((const char*)lds + Xr * 256 + ((y ^ (Xr & 15)) << 4));
    *(int4v*)(aq + obase + (size_t)a * KT * 1024 + tid * 16) = vv;
  }
}

__global__ __launch_bounds__(256) void pack_w_kernel(
    const int* __restrict__ w, signed char* __restrict__ wq) {
  __shared__ unsigned int lds[4096];
  int bid = blockIdx.x;
  int r0 = (bid >> 4) * 64;
  int k0 = (bid & 15) * 256;
  int tid = threadIdx.x, lane = tid & 63, wv = tid >> 6;

  int subL = wv * 4 + (lane >> 4);
  int kgroup = (lane & 15) >> 2;
  int c = lane & 3;
  int X = subL * 4 + kgroup;
  int xm = X & 15;
  const int* src = w + (size_t)(r0 + wv * 16) * KD + k0 + lane * 4;
#pragma unroll
  for (int i = 0; i < 16; ++i) {
    int4v v = *(const int4v*)(src + (size_t)i * KD);
    unsigned int d = (v.x & 0xff) | ((v.y & 0xff) << 8) |
                     ((v.z & 0xff) << 16) | ((v.w & 0xff) << 24);
    lds[X * 64 + ((i ^ xm) << 2) + c] = d;
  }
  __syncthreads();

  size_t obase = ((size_t)(r0 >> 4) * KT + (k0 >> 6)) * 1024;
  int y = tid & 15;
#pragma unroll
  for (int a = 0; a < 4; ++a) {
    int Xr = (a * 4 + (tid >> 6)) * 4 + ((tid & 63) >> 4);
    int4v vv = *(const int4v*)((const char*)lds + Xr * 256 + ((y ^ (Xr & 15)) << 4));
    *(int4v*)(wq + obase + (size_t)a * KT * 1024 + tid * 16) = vv;
  }
}

// GEMM v2: 256x256 tile, BK=64, 8 waves (2x4), per-wave 128x64 output
// (8x4 fragments of 16x16x64). Double-buffered LDS, stage(t+1) issued at
// loop top so HBM/L2 latency hides under ~2600 cy of MFMA.
#define STAGE(buf, kt) do {                                                   \
    _Pragma("unroll")                                                         \
    for (int j = 0; j < 2; ++j) {                                             \
      const signed char* ga =                                                 \
          aq + ((size_t)(a_sub0 + j * 8 + wv) * KT + (kt)) * 1024 + lane * 16;\
      __builtin_amdgcn_global_load_lds(                                       \
          (const __attribute__((address_space(1))) void*)ga,                  \
          (__attribute__((address_space(3))) void*)                           \
              (lds_g + (buf) * 32768 + (j * 8 + wv) * 1024), 16, 0, 0);       \
      const signed char* gb =                                                 \
          wq + ((size_t)(b_sub0 + j * 8 + wv) * KT + (kt)) * 1024 + lane * 16;\
      __builtin_amdgcn_global_load_lds(                                       \
          (const __attribute__((address_space(1))) void*)gb,                  \
          (__attribute__((address_space(3))) void*)                           \
              (lds_g + (buf) * 32768 + 16384 + (j * 8 + wv) * 1024), 16, 0, 0);\
    }                                                                         \
  } while (0)

__global__ __launch_bounds__(512, 2) void gemm_i8_kernel(
    const signed char* __restrict__ aq, const signed char* __restrict__ wq,
    const float* __restrict__ ws_p, const float* __restrict__ as_p,
    const float* __restrict__ bias, float* __restrict__ out) {
  __shared__ signed char lds_g[65536];   // [2 bufs][A 16KB | B 16KB]

  // XCD-bijective swizzle (gridDim = 512, divisible by 8)
  int nwg = gridDim.x;
  int cpx = nwg >> 3;
  int bid = blockIdx.x;
  int wg  = (bid & 7) * cpx + (bid >> 3);
  const int NT = ND / 256;      // 16
  int tm = wg / NT;
  int tn = wg - tm * NT;

  int tid  = threadIdx.x;
  int lane = tid & 63;
  int wv   = tid >> 6;          // wave 0..7
  int wr   = wv >> 2;           // wave row 0..1 (128-row half)
  int wc   = wv & 3;            // wave col 0..3 (64-col quarter)

  const int a_sub0 = tm * 16;   // 16 row-subtiles per 256-row tile
  const int b_sub0 = tn * 16;

  int4v acc[8][4];
#pragma unroll
  for (int i = 0; i < 8; ++i)
#pragma unroll
    for (int j = 0; j < 4; ++j) acc[i][j] = (int4v){0, 0, 0, 0};

  int cur = 0;
  STAGE(0, 0);
  __syncthreads();              // drains vmcnt(0): tile 0 resident

  for (int kt = 0; kt < KT; ++kt) {
    if (kt + 1 < KT) {
      STAGE(cur ^ 1, kt + 1);   // issue early; lands during this iter's MFMAs
    }
    __builtin_amdgcn_sched_barrier(0);  // pin stage issue before compute

    const signed char* abuf = lds_g + cur * 32768;
    const signed char* bbuf = abuf + 16384;

    int4v afrag[8], bfrag[4];
#pragma unroll
    for (int rb = 0; rb < 8; ++rb)
      afrag[rb] = *(const int4v*)(abuf + (wr * 8 + rb) * 1024 + lane * 16);
#pragma unroll
    for (int cb = 0; cb < 4; ++cb)
      bfrag[cb] = *(const int4v*)(bbuf + (wc * 4 + cb) * 1024 + lane * 16);

#pragma unroll
    for (int rb = 0; rb < 8; ++rb)
#pragma unroll
      for (int cb = 0; cb < 4; ++cb)
        acc[rb][cb] = __builtin_amdgcn_mfma_i32_16x16x64_i8(
            afrag[rb], bfrag[cb], acc[rb][cb], 0, 0, 0);

    __syncthreads();            // waits own vmcnt(0) (already landed) + barrier
    cur ^= 1;
  }

  // epilogue: C/D 16x16 layout: col = lane&15, row = (lane>>4)*4 + reg
  float scale = ws_p[0] * as_p[0];
  int col0 = tn * 256 + wc * 64 + (lane & 15);
  int row0 = tm * 256 + wr * 128 + ((lane >> 4) << 2);
  float bv[4];
#pragma unroll
  for (int cb = 0; cb < 4; ++cb) bv[cb] = bias[col0 + cb * 16];
#pragma unroll
  for (int rb = 0; rb < 8; ++rb) {
#pragma unroll
    for (int cb = 0; cb < 4; ++cb) {
      int col = col0 + cb * 16;
#pragma unroll
      for (int j = 0; j < 4; ++j) {
        int row = row0 + rb * 16 + j;
        out[(size_t)row * ND + col] = (float)acc[rb][cb][j] * scale + bv[cb];
      }
    }
  }
}

extern "C" void kernel_launch(void* const* d_in, const int* in_sizes, int n_in,
                              void* d_out, int out_size, void* d_ws, size_t ws_size,
                              hipStream_t stream) {
  const float* x    = (const float*)d_in[0];
  const int*   qw   = (const int*)d_in[1];
  const float* wsc  = (const float*)d_in[2];
  const float* asc  = (const float*)d_in[3];
  const float* bias = (const float*)d_in[4];
  float* out = (float*)d_out;

  signed char* aq = (signed char*)d_ws;                       // 32 MiB
  signed char* wq = aq + (size_t)MD * KD;                     // 16 MiB

  quant_x_kernel<<<(MD / 64) * (KD / 256), 256, 0, stream>>>(x, asc, aq);
  pack_w_kernel<<<(ND / 64) * (KD / 256), 256, 0, stream>>>(qw, wq);
  gemm_i8_kernel<<<(MD / 256) * (ND / 256), 512, 0, stream>>>(aq, wq, wsc, asc, bias, out);
}